// Round 1
// baseline (337.205 us; speedup 1.0000x reference)
//
#include <hip/hip_runtime.h>
#include <hip/hip_bf16.h>

#define BATCH 16
#define CIN 64
#define COUT 64
#define HH 160
#define WW 160
#define HP 162
#define WP 162

typedef __attribute__((ext_vector_type(8))) __bf16 bf16x8;
typedef __attribute__((ext_vector_type(4))) float f32x4;

// ---------------------------------------------------------------------------
// Pass 1: x (NCHW fp32) -> xs (B, 162, 162, C) bf16, per-channel shift folded
// into the padded layout. xs[b,y,x,c] = xp[b,c,(y-dy_c),(x-dx_c)] with the
// padding ring zero (mod-wrap provably always lands in the pad ring).
// ---------------------------------------------------------------------------
__global__ __launch_bounds__(256) void shift_cvt(const float* __restrict__ x,
                                                 unsigned short* __restrict__ xs) {
  int blk = blockIdx.x;
  int y = blk % HP;
  int b = blk / HP;
  int tid = threadIdx.x;
  int c = tid & 63;   // lanes 0..63 -> channels: 128B contiguous stores
  int xg = tid >> 6;  // 4 x-positions in flight per block
  int cm = c % 5;
  int dx = (cm == 1) ? 1 : ((cm == 3) ? -1 : 0);
  int dy = (cm == 2) ? 1 : ((cm == 4) ? -1 : 0);
  int yy = y - dy;  // need 1..160 for non-zero
  bool yok = (yy >= 1 && yy <= HH);
  const float* xrow = x + (((size_t)(b * CIN + c) * HH) + (size_t)(yy - 1)) * WW;
  size_t obase = ((size_t)(b * HP + y) * WP) * CIN + c;
  for (int xi = xg; xi < WP; xi += 4) {
    int xx = xi - dx;
    float v = 0.f;
    if (yok && xx >= 1 && xx <= WW) v = xrow[xx - 1];
    __hip_bfloat16 h = __float2bfloat16(v);
    xs[obase + (size_t)xi * CIN] = *reinterpret_cast<unsigned short*>(&h);
  }
}

// ---------------------------------------------------------------------------
// Weight: w (O, C, 3, 3) fp32 -> wb[tap][o][c] bf16  (tap = ky*3+kx)
// ---------------------------------------------------------------------------
__global__ __launch_bounds__(256) void wcvt(const float* __restrict__ w,
                                            unsigned short* __restrict__ wb) {
  int e = blockIdx.x * 256 + threadIdx.x;
  if (e >= 9 * 64 * 64) return;
  int tap = e >> 12;       // / 4096
  int o = (e >> 6) & 63;
  int c = e & 63;
  float v = w[((size_t)(o * 64 + c)) * 9 + tap];
  __hip_bfloat16 h = __float2bfloat16(v);
  wb[e] = *reinterpret_cast<unsigned short*>(&h);
}

// ---------------------------------------------------------------------------
// Pass 2: implicit-GEMM conv. Block = (b, 16x16 spatial tile) x all 64 ochans.
// M = 256 pixels (m = li*16+lj), N = 64, K = 9 taps x 64 c, chunked K=32.
// LDS: 18x18 input pixels x 64ch, pixel stride padded to 72 (bank-balanced).
// A-frags from LDS (ds_read_b128), B-frags from global (L2-resident 73KB).
// mfma_f32_16x16x32_bf16: A[m=lane&15][k=q*8+j], B[k=q*8+j][n=lane&15],
// D[row=q*4+r][col=lane&15]  (m89/m91-verified layout).
// ---------------------------------------------------------------------------
__global__ __launch_bounds__(256, 3) void conv_mfma(const unsigned short* __restrict__ xs,
                                                    const unsigned short* __restrict__ wb,
                                                    float* __restrict__ out) {
  __shared__ unsigned short lds_in[324 * 72];  // 46,656 B

  int tj = blockIdx.x, ti = blockIdx.y, b = blockIdx.z;
  int tid = threadIdx.x;
  int y0 = ti * 16, x0 = tj * 16;

  // ---- stage 18x18x64 bf16 tile: 324 pixels * 128B = 2592 x 16B units ----
  const size_t xs_b = ((size_t)b * HP) * WP * CIN;
  for (int u = tid; u < 2592; u += 256) {
    int p = u >> 3, q8 = u & 7;
    int pr = p / 18, pc = p - pr * 18;
    uint4 v = *reinterpret_cast<const uint4*>(
        xs + xs_b + ((size_t)(y0 + pr) * WP + (size_t)(x0 + pc)) * CIN + q8 * 8);
    *reinterpret_cast<uint4*>(&lds_in[p * 72 + q8 * 8]) = v;
  }
  __syncthreads();

  int wv = tid >> 6;       // wave 0..3 -> li in [4w, 4w+4)
  int lane = tid & 63;
  int l15 = lane & 15;
  int q = lane >> 4;

  f32x4 acc[4][4];
#pragma unroll
  for (int a = 0; a < 4; ++a)
#pragma unroll
    for (int bb = 0; bb < 4; ++bb) acc[a][bb] = (f32x4){0.f, 0.f, 0.f, 0.f};

  for (int tap = 0; tap < 9; ++tap) {
    int ky = tap / 3, kx = tap - ky * 3;
#pragma unroll
    for (int ch = 0; ch < 2; ++ch) {
      int c0 = ch * 32;
      bf16x8 A[4], Bf[4];
#pragma unroll
      for (int mt = 0; mt < 4; ++mt) {
        int li = 4 * wv + mt;
        A[mt] = *reinterpret_cast<const bf16x8*>(
            &lds_in[((li + ky) * 18 + (l15 + kx)) * 72 + c0 + q * 8]);
      }
#pragma unroll
      for (int nt = 0; nt < 4; ++nt) {
        Bf[nt] = *reinterpret_cast<const bf16x8*>(
            wb + ((size_t)tap * 64 + (size_t)(nt * 16 + l15)) * 64 + c0 + q * 8);
      }
#pragma unroll
      for (int mt = 0; mt < 4; ++mt)
#pragma unroll
        for (int nt = 0; nt < 4; ++nt)
          acc[mt][nt] = __builtin_amdgcn_mfma_f32_16x16x32_bf16(A[mt], Bf[nt], acc[mt][nt], 0, 0, 0);
    }
  }

  // ---- epilogue: D[row=q*4+r][col=l15]; row = lj (x-offset), tile row = li ----
#pragma unroll
  for (int mt = 0; mt < 4; ++mt) {
    int i = y0 + 4 * wv + mt;
#pragma unroll
    for (int nt = 0; nt < 4; ++nt) {
      int o = nt * 16 + l15;
      size_t addr = (((size_t)(b * COUT + o) * HH) + (size_t)i) * WW + (size_t)(x0 + q * 4);
      *reinterpret_cast<f32x4*>(out + addr) = acc[mt][nt];
    }
  }
}

extern "C" void kernel_launch(void* const* d_in, const int* in_sizes, int n_in,
                              void* d_out, int out_size, void* d_ws, size_t ws_size,
                              hipStream_t stream) {
  const float* x = (const float*)d_in[0];
  const float* w = (const float*)d_in[1];
  float* out = (float*)d_out;

  unsigned short* xs = (unsigned short*)d_ws;  // 16*162*162*64 bf16 = 53.7 MB
  unsigned short* wb = (unsigned short*)((char*)d_ws + (size_t)BATCH * HP * WP * CIN * 2);

  hipLaunchKernelGGL(shift_cvt, dim3(BATCH * HP), dim3(256), 0, stream, x, xs);
  hipLaunchKernelGGL(wcvt, dim3(144), dim3(256), 0, stream, w, wb);
  hipLaunchKernelGGL(conv_mfma, dim3(10, 10, BATCH), dim3(256), 0, stream, xs, wb, out);
}

// Round 2
// 288.942 us; speedup vs baseline: 1.1670x; 1.1670x over previous
//
#include <hip/hip_runtime.h>
#include <hip/hip_bf16.h>

#define BATCH 16
#define CIN 64
#define COUT 64
#define HH 160
#define WW 160
#define HP 162
#define WP 162

typedef __attribute__((ext_vector_type(8))) __bf16 bf16x8;
typedef __attribute__((ext_vector_type(4))) float f32x4;

// ---------------------------------------------------------------------------
// Pass 1 (v2): x (NCHW fp32) -> xs (B, 162, 162, C) bf16, shift folded in.
// LDS-transposed: coalesced float4 reads along W, coalesced 128B/wave bf16
// stores along C. XOR swizzle (j ^ (c&7)) on float4 columns kills the 8-way
// bank conflict that stride-160 rows would otherwise have in the read phase
// (row stride 160 dwords = 0 mod 32 banks).
// Each source row (b,c,yy) feeds exactly one output row y = yy + dy_c, so
// HBM read traffic is exactly 105 MB (no re-fetch).
// ---------------------------------------------------------------------------
__global__ __launch_bounds__(256) void shift_cvt(const float* __restrict__ x,
                                                 unsigned short* __restrict__ xs) {
  __shared__ float lds[64 * 160];  // 40 KB
  int y = blockIdx.x % HP;
  int b = blockIdx.x / HP;
  int tid = threadIdx.x;

  // ---- load: global (coalesced along W) -> LDS, zeroing out-of-range rows --
#pragma unroll
  for (int it = 0; it < 10; ++it) {
    int idx = it * 256 + tid;  // 0..2559 = 64 channels x 40 float4
    int c = idx / 40;
    int j = idx - c * 40;
    int cm = c % 5;
    int dy = (cm == 2) ? 1 : ((cm == 4) ? -1 : 0);
    int yy = y - dy;  // source row (1..160 valid)
    f32x4 v = {0.f, 0.f, 0.f, 0.f};
    if (yy >= 1 && yy <= HH)
      v = *reinterpret_cast<const f32x4*>(
          x + (((size_t)(b * CIN + c)) * HH + (size_t)(yy - 1)) * WW + j * 4);
    *reinterpret_cast<f32x4*>(&lds[c * 160 + 4 * (j ^ (c & 7))]) = v;
  }
  __syncthreads();

  // ---- store: LDS -> xs (lanes along C, 128B/wave coalesced) --------------
  int c = tid & 63;
  int wv = tid >> 6;
  int cm = c % 5;
  int dx = (cm == 1) ? 1 : ((cm == 3) ? -1 : 0);
  int sw = c & 7;
  size_t obase = ((size_t)(b * HP + y) * WP) * CIN + c;
  const float* lrow = &lds[c * 160];
  for (int xi = wv; xi < WP; xi += 4) {
    int xx = xi - dx - 1;  // source x (0..159 valid)
    float v = 0.f;
    if (xx >= 0 && xx < WW) v = lrow[4 * ((xx >> 2) ^ sw) + (xx & 3)];
    __hip_bfloat16 h = __float2bfloat16(v);
    xs[obase + (size_t)xi * CIN] = *reinterpret_cast<unsigned short*>(&h);
  }
}

// ---------------------------------------------------------------------------
// Weight: w (O, C, 3, 3) fp32 -> wb[tap][o][c] bf16  (tap = ky*3+kx)
// ---------------------------------------------------------------------------
__global__ __launch_bounds__(256) void wcvt(const float* __restrict__ w,
                                            unsigned short* __restrict__ wb) {
  int e = blockIdx.x * 256 + threadIdx.x;
  if (e >= 9 * 64 * 64) return;
  int tap = e >> 12;  // / 4096
  int o = (e >> 6) & 63;
  int c = e & 63;
  float v = w[((size_t)(o * 64 + c)) * 9 + tap];
  __hip_bfloat16 h = __float2bfloat16(v);
  wb[e] = *reinterpret_cast<unsigned short*>(&h);
}

// ---------------------------------------------------------------------------
// Pass 2: implicit-GEMM conv (unchanged this round — measured next).
// Block = (b, 16x16 spatial tile) x all 64 ochans.
// M = 256 pixels, N = 64, K = 9 taps x 64 c, chunked K=32.
// LDS: 18x18 pixels x 64ch bf16, pixel stride padded to 72.
// mfma_f32_16x16x32_bf16: A[m=lane&15][k=q*8+j], B[k][n=lane&15],
// D[row=q*4+r][col=lane&15]  (m89/m91-verified layout).
// ---------------------------------------------------------------------------
__global__ __launch_bounds__(256, 3) void conv_mfma(const unsigned short* __restrict__ xs,
                                                    const unsigned short* __restrict__ wb,
                                                    float* __restrict__ out) {
  __shared__ unsigned short lds_in[324 * 72];  // 46,656 B

  int tj = blockIdx.x, ti = blockIdx.y, b = blockIdx.z;
  int tid = threadIdx.x;
  int y0 = ti * 16, x0 = tj * 16;

  // ---- stage 18x18x64 bf16 tile: 324 pixels * 128B = 2592 x 16B units ----
  const size_t xs_b = ((size_t)b * HP) * WP * CIN;
  for (int u = tid; u < 2592; u += 256) {
    int p = u >> 3, q8 = u & 7;
    int pr = p / 18, pc = p - pr * 18;
    uint4 v = *reinterpret_cast<const uint4*>(
        xs + xs_b + ((size_t)(y0 + pr) * WP + (size_t)(x0 + pc)) * CIN + q8 * 8);
    *reinterpret_cast<uint4*>(&lds_in[p * 72 + q8 * 8]) = v;
  }
  __syncthreads();

  int wv = tid >> 6;  // wave 0..3 -> li in [4w, 4w+4)
  int lane = tid & 63;
  int l15 = lane & 15;
  int q = lane >> 4;

  f32x4 acc[4][4];
#pragma unroll
  for (int a = 0; a < 4; ++a)
#pragma unroll
    for (int bb = 0; bb < 4; ++bb) acc[a][bb] = (f32x4){0.f, 0.f, 0.f, 0.f};

  for (int tap = 0; tap < 9; ++tap) {
    int ky = tap / 3, kx = tap - ky * 3;
#pragma unroll
    for (int ch = 0; ch < 2; ++ch) {
      int c0 = ch * 32;
      bf16x8 A[4], Bf[4];
#pragma unroll
      for (int mt = 0; mt < 4; ++mt) {
        int li = 4 * wv + mt;
        A[mt] = *reinterpret_cast<const bf16x8*>(
            &lds_in[((li + ky) * 18 + (l15 + kx)) * 72 + c0 + q * 8]);
      }
#pragma unroll
      for (int nt = 0; nt < 4; ++nt) {
        Bf[nt] = *reinterpret_cast<const bf16x8*>(
            wb + ((size_t)tap * 64 + (size_t)(nt * 16 + l15)) * 64 + c0 + q * 8);
      }
#pragma unroll
      for (int mt = 0; mt < 4; ++mt)
#pragma unroll
        for (int nt = 0; nt < 4; ++nt)
          acc[mt][nt] = __builtin_amdgcn_mfma_f32_16x16x32_bf16(A[mt], Bf[nt], acc[mt][nt], 0, 0, 0);
    }
  }

  // ---- epilogue: D[row=q*4+r][col=l15] ----
#pragma unroll
  for (int mt = 0; mt < 4; ++mt) {
    int i = y0 + 4 * wv + mt;
#pragma unroll
    for (int nt = 0; nt < 4; ++nt) {
      int o = nt * 16 + l15;
      size_t addr = (((size_t)(b * COUT + o) * HH) + (size_t)i) * WW + (size_t)(x0 + q * 4);
      *reinterpret_cast<f32x4*>(out + addr) = acc[mt][nt];
    }
  }
}

extern "C" void kernel_launch(void* const* d_in, const int* in_sizes, int n_in,
                              void* d_out, int out_size, void* d_ws, size_t ws_size,
                              hipStream_t stream) {
  const float* x = (const float*)d_in[0];
  const float* w = (const float*)d_in[1];
  float* out = (float*)d_out;

  unsigned short* xs = (unsigned short*)d_ws;  // 16*162*162*64 bf16 = 53.7 MB
  unsigned short* wb = (unsigned short*)((char*)d_ws + (size_t)BATCH * HP * WP * CIN * 2);

  hipLaunchKernelGGL(shift_cvt, dim3(BATCH * HP), dim3(256), 0, stream, x, xs);
  hipLaunchKernelGGL(wcvt, dim3(144), dim3(256), 0, stream, w, wb);
  hipLaunchKernelGGL(conv_mfma, dim3(10, 10, BATCH), dim3(256), 0, stream, xs, wb, out);
}